// Round 3
// baseline (586.079 us; speedup 1.0000x reference)
//
#include <hip/hip_runtime.h>
#include <hip/hip_bf16.h>
#include <stdint.h>

#define IN_F 128
#define EDGE_F 6
#define KC 136          // 128 node feats + 6 edge feats + deg + pad
#define NPB 32          // dst nodes per block in gather_gemm

__device__ __forceinline__ float bf2f(unsigned short u) {
    return __uint_as_float(((unsigned int)u) << 16);
}
__device__ __forceinline__ unsigned short f2bfbits(float f) {
    __hip_bfloat16 h = __float2bfloat16(f);  // RNE
    return *reinterpret_cast<unsigned short*>(&h);
}

// ---- Phase 1: per-dst degree histogram + edge-feature sums (7 atomics/edge) ----
__global__ __launch_bounds__(256) void hist_e6(
        const int* __restrict__ eidx, const float* __restrict__ ef,
        int* __restrict__ cnt, float* __restrict__ E8, int n_edges) {
    int e = blockIdx.x * 256 + threadIdx.x;
    if (e >= n_edges) return;
    int dst = eidx[2 * e + 1];
    atomicAdd(&cnt[dst], 1);
#pragma unroll
    for (int f = 0; f < EDGE_F; ++f)
        atomicAdd(&E8[dst * 8 + f], ef[(size_t)e * EDGE_F + f]);
}

// ---- Phase 2: two-level exclusive scan of cnt -> rowptr (+cursor copy) ----
__global__ __launch_bounds__(256) void scan_a(
        const int* __restrict__ cnt, int* __restrict__ bsum, int n) {
    __shared__ int sh[256];
    int tid = threadIdx.x;
    int i = blockIdx.x * 256 + tid;
    sh[tid] = (i < n) ? cnt[i] : 0;
    __syncthreads();
    for (int off = 128; off > 0; off >>= 1) {
        if (tid < off) sh[tid] += sh[tid + off];
        __syncthreads();
    }
    if (tid == 0) bsum[blockIdx.x] = sh[0];
}

__global__ __launch_bounds__(256) void scan_b(
        const int* __restrict__ bsum, int* __restrict__ boff, int nblocks) {
    __shared__ int sh[256];
    int tid = threadIdx.x;
    int v = (tid < nblocks) ? bsum[tid] : 0;
    sh[tid] = v;
    __syncthreads();
    for (int off = 1; off < 256; off <<= 1) {
        int t = (tid >= off) ? sh[tid - off] : 0;
        __syncthreads();
        sh[tid] += t;
        __syncthreads();
    }
    boff[tid] = sh[tid] - v;  // exclusive
}

__global__ __launch_bounds__(256) void scan_c(
        const int* __restrict__ cnt, const int* __restrict__ boff,
        int* __restrict__ rowptr, int* __restrict__ cursor, int n) {
    __shared__ int sh[256];
    int tid = threadIdx.x;
    int i = blockIdx.x * 256 + tid;
    int v = (i < n) ? cnt[i] : 0;
    sh[tid] = v;
    __syncthreads();
    for (int off = 1; off < 256; off <<= 1) {
        int t = (tid >= off) ? sh[tid - off] : 0;
        __syncthreads();
        sh[tid] += t;
        __syncthreads();
    }
    int rp = boff[blockIdx.x] + sh[tid] - v;  // exclusive global prefix
    if (i < n) {
        rowptr[i] = rp;
        cursor[i] = rp;
        if (i == n - 1) rowptr[n] = rp + v;
    }
}

// ---- Phase 3: scatter edge src ids into CSR order ----
__global__ __launch_bounds__(256) void fill_csr(
        const int* __restrict__ eidx, int* __restrict__ cursor,
        int* __restrict__ esrc, int n_edges) {
    int e = blockIdx.x * 256 + threadIdx.x;
    if (e >= n_edges) return;
    int src = eidx[2 * e];
    int dst = eidx[2 * e + 1];
    int pos = atomicAdd(&cursor[dst], 1);
    esrc[pos] = src;
}

// ---- Phase 4: fused gather-aggregate + GEMM + ReLU ----
// Block = 256 threads handles NPB=32 dst nodes. Gather: 8 groups of 32 lanes,
// group g aggregates nodes nl = g+8j (j=0..3); lane covers features 4L..4L+3.
// Then Xl[32][136] x Wl[136][128] -> out, 4x4 register tile per thread.
__global__ __launch_bounds__(256) void gather_gemm(
        const float* __restrict__ nf, const int* __restrict__ esrc,
        const int* __restrict__ rowptr, const float* __restrict__ E8,
        const float* __restrict__ W, const float* __restrict__ b,
        const float* __restrict__ We, const float* __restrict__ be,
        float* __restrict__ out, int n_nodes) {
    __shared__ __align__(16) unsigned short Wl[KC * 128];
    __shared__ __align__(16) float Xl[NPB * KC];
    const int tid = threadIdx.x;

    // Stage Wcat = [W ; We ; b+be ; 0] as bf16.
    for (int idx = tid; idx < KC * 128; idx += 256) {
        int k = idx >> 7, c = idx & 127;
        unsigned short v;
        if (k < 128)       v = f2bfbits(W[k * 128 + c]);
        else if (k < 134)  v = f2bfbits(We[(k - 128) * 128 + c]);
        else if (k == 134) v = f2bfbits(b[c] + be[c]);
        else               v = 0;
        Wl[idx] = v;
    }

    const int nb0 = blockIdx.x * NPB;
    const int lane = tid & 31;
    const int grp = tid >> 5;  // 0..7

#pragma unroll
    for (int j = 0; j < 4; ++j) {
        const int nl = grp + 8 * j;
        const int n = nb0 + nl;
        float4 a0 = {0.f, 0.f, 0.f, 0.f}, a1 = {0.f, 0.f, 0.f, 0.f};
        int deg = 0;
        if (n < n_nodes) {
            const int r0 = rowptr[n], r1 = rowptr[n + 1];
            deg = r1 - r0;
            int i = r0;
            for (; i + 1 < r1; i += 2) {  // 2-way unroll: two loads in flight
                const int s0 = esrc[i], s1 = esrc[i + 1];
                const float4 v0 = reinterpret_cast<const float4*>(nf + (size_t)s0 * IN_F)[lane];
                const float4 v1 = reinterpret_cast<const float4*>(nf + (size_t)s1 * IN_F)[lane];
                a0.x += v0.x; a0.y += v0.y; a0.z += v0.z; a0.w += v0.w;
                a1.x += v1.x; a1.y += v1.y; a1.z += v1.z; a1.w += v1.w;
            }
            if (i < r1) {
                const int s0 = esrc[i];
                const float4 v0 = reinterpret_cast<const float4*>(nf + (size_t)s0 * IN_F)[lane];
                a0.x += v0.x; a0.y += v0.y; a0.z += v0.z; a0.w += v0.w;
            }
        }
        float4 a;
        a.x = a0.x + a1.x; a.y = a0.y + a1.y; a.z = a0.z + a1.z; a.w = a0.w + a1.w;
        *reinterpret_cast<float4*>(&Xl[nl * KC + 4 * lane]) = a;
        if (lane < 6)       Xl[nl * KC + 128 + lane] = (n < n_nodes) ? E8[n * 8 + lane] : 0.f;
        else if (lane == 6) Xl[nl * KC + 134] = (float)deg;
        else if (lane == 7) Xl[nl * KC + 135] = 0.f;
    }
    __syncthreads();  // Xl + Wl ready

    const int f0 = (tid & 31) * 4;
    const int ngrp = tid >> 5;

    float acc[4][4];
#pragma unroll
    for (int j = 0; j < 4; ++j)
#pragma unroll
        for (int i = 0; i < 4; ++i) acc[j][i] = 0.f;

    for (int k = 0; k < KC; ++k) {
        const ushort4 wu = *reinterpret_cast<const ushort4*>(&Wl[k * 128 + f0]);
        const float w0 = bf2f(wu.x), w1 = bf2f(wu.y), w2 = bf2f(wu.z), w3 = bf2f(wu.w);
#pragma unroll
        for (int j = 0; j < 4; ++j) {
            const float x = Xl[(ngrp + 8 * j) * KC + k];
            acc[j][0] += x * w0;
            acc[j][1] += x * w1;
            acc[j][2] += x * w2;
            acc[j][3] += x * w3;
        }
    }

#pragma unroll
    for (int j = 0; j < 4; ++j) {
        const int n = nb0 + ngrp + 8 * j;
        if (n < n_nodes) {
            float4 o;
            o.x = fmaxf(acc[j][0], 0.f);
            o.y = fmaxf(acc[j][1], 0.f);
            o.z = fmaxf(acc[j][2], 0.f);
            o.w = fmaxf(acc[j][3], 0.f);
            *reinterpret_cast<float4*>(&out[(size_t)n * 128 + f0]) = o;
        }
    }
}

extern "C" void kernel_launch(void* const* d_in, const int* in_sizes, int n_in,
                              void* d_out, int out_size, void* d_ws, size_t ws_size,
                              hipStream_t stream) {
    const float* nf = (const float*)d_in[0];  // fp32 (N,128)
    const int* eidx = (const int*)d_in[1];    // int32 (E,2)
    const float* ef = (const float*)d_in[2];  // fp32 (E,6)
    const float* W  = (const float*)d_in[3];  // fp32 (128,128)
    const float* b  = (const float*)d_in[4];  // fp32 (128,)
    const float* We = (const float*)d_in[5];  // fp32 (6,128)
    const float* be = (const float*)d_in[6];  // fp32 (128,)
    float* out = (float*)d_out;               // fp32 (N,128)

    const int n_nodes = in_sizes[0] / IN_F;
    const int n_edges = in_sizes[1] / 2;

    // ws layout: [cnt N][E8 8N floats] (zeroed) | rowptr N+1 | cursor N | bsum 256 | boff 256 | esrc E
    int* cnt    = (int*)d_ws;
    float* E8   = (float*)(cnt + n_nodes);
    int* rowptr = (int*)(E8 + (size_t)n_nodes * 8);
    int* cursor = rowptr + n_nodes + 1;
    int* bsum   = cursor + n_nodes;
    int* boff   = bsum + 256;
    int* esrc   = boff + 256;

    hipMemsetAsync(d_ws, 0, (size_t)n_nodes * 36, stream);  // cnt + E8

    const int eb = (n_edges + 255) / 256;
    const int nb = (n_nodes + 255) / 256;  // 196 <= 256 (scan_b capacity)

    hist_e6<<<eb, 256, 0, stream>>>(eidx, ef, cnt, E8, n_edges);
    scan_a<<<nb, 256, 0, stream>>>(cnt, bsum, n_nodes);
    scan_b<<<1, 256, 0, stream>>>(bsum, boff, nb);
    scan_c<<<nb, 256, 0, stream>>>(cnt, boff, rowptr, cursor, n_nodes);
    fill_csr<<<eb, 256, 0, stream>>>(eidx, cursor, esrc, n_edges);

    const int nt = (n_nodes + NPB - 1) / NPB;
    gather_gemm<<<nt, 256, 0, stream>>>(nf, esrc, rowptr, E8, W, b, We, be, out, n_nodes);
}

// Round 4
// 330.502 us; speedup vs baseline: 1.7733x; 1.7733x over previous
//
#include <hip/hip_runtime.h>
#include <hip/hip_bf16.h>
#include <stdint.h>

#define IN_F 128
#define EDGE_F 6
#define KC 136          // 128 node feats + 6 edge feats + deg + pad
#define NPB 32          // dst nodes per block in gather_gemm

__device__ __forceinline__ float bf2f(unsigned short u) {
    return __uint_as_float(((unsigned int)u) << 16);
}
__device__ __forceinline__ unsigned short f2bfbits(float f) {
    __hip_bfloat16 h = __float2bfloat16(f);  // RNE
    return *reinterpret_cast<unsigned short*>(&h);
}

// ---- Phase 1: per-dst degree histogram (1 atomic/edge) ----
__global__ __launch_bounds__(256) void hist(
        const int* __restrict__ eidx, int* __restrict__ cnt, int n_edges) {
    int e = blockIdx.x * 256 + threadIdx.x;
    if (e >= n_edges) return;
    atomicAdd(&cnt[eidx[2 * e + 1]], 1);
}

// ---- Phase 2: two-level exclusive scan of cnt -> rowptr (+cursor copy) ----
__global__ __launch_bounds__(256) void scan_a(
        const int* __restrict__ cnt, int* __restrict__ bsum, int n) {
    __shared__ int sh[256];
    int tid = threadIdx.x;
    int i = blockIdx.x * 256 + tid;
    sh[tid] = (i < n) ? cnt[i] : 0;
    __syncthreads();
    for (int off = 128; off > 0; off >>= 1) {
        if (tid < off) sh[tid] += sh[tid + off];
        __syncthreads();
    }
    if (tid == 0) bsum[blockIdx.x] = sh[0];
}

__global__ __launch_bounds__(256) void scan_b(
        const int* __restrict__ bsum, int* __restrict__ boff, int nblocks) {
    __shared__ int sh[256];
    int tid = threadIdx.x;
    int v = (tid < nblocks) ? bsum[tid] : 0;
    sh[tid] = v;
    __syncthreads();
    for (int off = 1; off < 256; off <<= 1) {
        int t = (tid >= off) ? sh[tid - off] : 0;
        __syncthreads();
        sh[tid] += t;
        __syncthreads();
    }
    boff[tid] = sh[tid] - v;  // exclusive
}

__global__ __launch_bounds__(256) void scan_c(
        const int* __restrict__ cnt, const int* __restrict__ boff,
        int* __restrict__ rowptr, int* __restrict__ cursor, int n) {
    __shared__ int sh[256];
    int tid = threadIdx.x;
    int i = blockIdx.x * 256 + tid;
    int v = (i < n) ? cnt[i] : 0;
    sh[tid] = v;
    __syncthreads();
    for (int off = 1; off < 256; off <<= 1) {
        int t = (tid >= off) ? sh[tid - off] : 0;
        __syncthreads();
        sh[tid] += t;
        __syncthreads();
    }
    int rp = boff[blockIdx.x] + sh[tid] - v;  // exclusive global prefix
    if (i < n) {
        rowptr[i] = rp;
        cursor[i] = rp;
        if (i == n - 1) rowptr[n] = rp + v;
    }
}

// ---- Phase 3: scatter src ids AND edge features into CSR order ----
// Scattered stores are fire-and-forget (no latency stall), unlike atomics.
__global__ __launch_bounds__(256) void fill_csr(
        const int* __restrict__ eidx, const float* __restrict__ ef,
        int* __restrict__ cursor, int* __restrict__ esrc,
        float* __restrict__ efo, int n_edges) {
    int e = blockIdx.x * 256 + threadIdx.x;
    if (e >= n_edges) return;
    const int2 pr = reinterpret_cast<const int2*>(eidx)[e];  // (src, dst)
    const float2* efs = reinterpret_cast<const float2*>(ef + (size_t)e * EDGE_F);
    const float2 f0 = efs[0], f1 = efs[1], f2 = efs[2];
    int pos = atomicAdd(&cursor[pr.y], 1);
    esrc[pos] = pr.x;
    float2* eo = reinterpret_cast<float2*>(efo + (size_t)pos * EDGE_F);
    eo[0] = f0; eo[1] = f1; eo[2] = f2;
}

// ---- Phase 4: fused gather-aggregate + GEMM + ReLU ----
// Block = 256 threads handles NPB=32 dst nodes. Gather: 8 groups of 32 lanes,
// group g aggregates nodes nl = g+8j (j=0..3); lane covers nf feats 4L..4L+3;
// lanes 0..5 also accumulate the CSR-ordered edge features.
// Then Xl[32][136] x Wl[136][128] -> out, 4x4 register tile per thread.
__global__ __launch_bounds__(256) void gather_gemm(
        const float* __restrict__ nf, const int* __restrict__ esrc,
        const int* __restrict__ rowptr, const float* __restrict__ efo,
        const float* __restrict__ W, const float* __restrict__ b,
        const float* __restrict__ We, const float* __restrict__ be,
        float* __restrict__ out, int n_nodes) {
    __shared__ __align__(16) unsigned short Wl[KC * 128];
    __shared__ __align__(16) float Xl[NPB * KC];
    const int tid = threadIdx.x;

    // Stage Wcat = [W ; We ; b+be ; 0] as bf16.
    for (int idx = tid; idx < KC * 128; idx += 256) {
        int k = idx >> 7, c = idx & 127;
        unsigned short v;
        if (k < 128)       v = f2bfbits(W[k * 128 + c]);
        else if (k < 134)  v = f2bfbits(We[(k - 128) * 128 + c]);
        else if (k == 134) v = f2bfbits(b[c] + be[c]);
        else               v = 0;
        Wl[idx] = v;
    }

    const int nb0 = blockIdx.x * NPB;
    const int lane = tid & 31;
    const int grp = tid >> 5;  // 0..7

#pragma unroll
    for (int j = 0; j < 4; ++j) {
        const int nl = grp + 8 * j;
        const int n = nb0 + nl;
        float4 a0 = {0.f, 0.f, 0.f, 0.f}, a1 = {0.f, 0.f, 0.f, 0.f};
        float4 a2 = {0.f, 0.f, 0.f, 0.f}, a3 = {0.f, 0.f, 0.f, 0.f};
        float e0 = 0.f, e1 = 0.f, e2 = 0.f, e3 = 0.f;
        int deg = 0;
        if (n < n_nodes) {
            const int r0 = rowptr[n], r1 = rowptr[n + 1];
            deg = r1 - r0;
            int i = r0;
            for (; i + 3 < r1; i += 4) {  // 4 rows in flight
                const int s0 = esrc[i], s1 = esrc[i + 1];
                const int s2 = esrc[i + 2], s3 = esrc[i + 3];
                const float4 v0 = reinterpret_cast<const float4*>(nf + (size_t)s0 * IN_F)[lane];
                const float4 v1 = reinterpret_cast<const float4*>(nf + (size_t)s1 * IN_F)[lane];
                const float4 v2 = reinterpret_cast<const float4*>(nf + (size_t)s2 * IN_F)[lane];
                const float4 v3 = reinterpret_cast<const float4*>(nf + (size_t)s3 * IN_F)[lane];
                if (lane < EDGE_F) {
                    e0 += efo[(size_t)(i)     * EDGE_F + lane];
                    e1 += efo[(size_t)(i + 1) * EDGE_F + lane];
                    e2 += efo[(size_t)(i + 2) * EDGE_F + lane];
                    e3 += efo[(size_t)(i + 3) * EDGE_F + lane];
                }
                a0.x += v0.x; a0.y += v0.y; a0.z += v0.z; a0.w += v0.w;
                a1.x += v1.x; a1.y += v1.y; a1.z += v1.z; a1.w += v1.w;
                a2.x += v2.x; a2.y += v2.y; a2.z += v2.z; a2.w += v2.w;
                a3.x += v3.x; a3.y += v3.y; a3.z += v3.z; a3.w += v3.w;
            }
            for (; i < r1; ++i) {
                const int s0 = esrc[i];
                const float4 v0 = reinterpret_cast<const float4*>(nf + (size_t)s0 * IN_F)[lane];
                if (lane < EDGE_F) e0 += efo[(size_t)i * EDGE_F + lane];
                a0.x += v0.x; a0.y += v0.y; a0.z += v0.z; a0.w += v0.w;
            }
        }
        float4 a;
        a.x = (a0.x + a1.x) + (a2.x + a3.x);
        a.y = (a0.y + a1.y) + (a2.y + a3.y);
        a.z = (a0.z + a1.z) + (a2.z + a3.z);
        a.w = (a0.w + a1.w) + (a2.w + a3.w);
        *reinterpret_cast<float4*>(&Xl[nl * KC + 4 * lane]) = a;
        if (lane < EDGE_F)       Xl[nl * KC + 128 + lane] = (e0 + e1) + (e2 + e3);
        else if (lane == EDGE_F) Xl[nl * KC + 134] = (float)deg;
        else if (lane == 7)      Xl[nl * KC + 135] = 0.f;
    }
    __syncthreads();  // Xl + Wl ready

    const int f0 = (tid & 31) * 4;
    const int ngrp = tid >> 5;

    float acc[4][4];
#pragma unroll
    for (int j = 0; j < 4; ++j)
#pragma unroll
        for (int i = 0; i < 4; ++i) acc[j][i] = 0.f;

    for (int k = 0; k < KC; ++k) {
        const ushort4 wu = *reinterpret_cast<const ushort4*>(&Wl[k * 128 + f0]);
        const float w0 = bf2f(wu.x), w1 = bf2f(wu.y), w2 = bf2f(wu.z), w3 = bf2f(wu.w);
#pragma unroll
        for (int j = 0; j < 4; ++j) {
            const float x = Xl[(ngrp + 8 * j) * KC + k];
            acc[j][0] += x * w0;
            acc[j][1] += x * w1;
            acc[j][2] += x * w2;
            acc[j][3] += x * w3;
        }
    }

#pragma unroll
    for (int j = 0; j < 4; ++j) {
        const int n = nb0 + ngrp + 8 * j;
        if (n < n_nodes) {
            float4 o;
            o.x = fmaxf(acc[j][0], 0.f);
            o.y = fmaxf(acc[j][1], 0.f);
            o.z = fmaxf(acc[j][2], 0.f);
            o.w = fmaxf(acc[j][3], 0.f);
            *reinterpret_cast<float4*>(&out[(size_t)n * 128 + f0]) = o;
        }
    }
}

extern "C" void kernel_launch(void* const* d_in, const int* in_sizes, int n_in,
                              void* d_out, int out_size, void* d_ws, size_t ws_size,
                              hipStream_t stream) {
    const float* nf = (const float*)d_in[0];  // fp32 (N,128)
    const int* eidx = (const int*)d_in[1];    // int32 (E,2)
    const float* ef = (const float*)d_in[2];  // fp32 (E,6)
    const float* W  = (const float*)d_in[3];  // fp32 (128,128)
    const float* b  = (const float*)d_in[4];  // fp32 (128,)
    const float* We = (const float*)d_in[5];  // fp32 (6,128)
    const float* be = (const float*)d_in[6];  // fp32 (128,)
    float* out = (float*)d_out;               // fp32 (N,128)

    const int n_nodes = in_sizes[0] / IN_F;
    const int n_edges = in_sizes[1] / 2;

    // ws layout: cnt N | rowptr N+1 | cursor N | bsum 256 | boff 256 | esrc E | efo 6E floats
    int* cnt    = (int*)d_ws;
    int* rowptr = cnt + n_nodes;
    int* cursor = rowptr + n_nodes + 1;
    int* bsum   = cursor + n_nodes;
    int* boff   = bsum + 256;
    int* esrc   = boff + 256;
    float* efo  = (float*)(esrc + n_edges);

    hipMemsetAsync(cnt, 0, (size_t)n_nodes * 4, stream);

    const int eb = (n_edges + 255) / 256;
    const int nb = (n_nodes + 255) / 256;  // 196 <= 256 (scan_b capacity)

    hist<<<eb, 256, 0, stream>>>(eidx, cnt, n_edges);
    scan_a<<<nb, 256, 0, stream>>>(cnt, bsum, n_nodes);
    scan_b<<<1, 256, 0, stream>>>(bsum, boff, nb);
    scan_c<<<nb, 256, 0, stream>>>(cnt, boff, rowptr, cursor, n_nodes);
    fill_csr<<<eb, 256, 0, stream>>>(eidx, ef, cursor, esrc, efo, n_edges);

    const int nt = (n_nodes + NPB - 1) / NPB;
    gather_gemm<<<nt, 256, 0, stream>>>(nf, esrc, rowptr, efo, W, b, We, be, out, n_nodes);
}

// Round 5
// 302.122 us; speedup vs baseline: 1.9399x; 1.0939x over previous
//
#include <hip/hip_runtime.h>
#include <hip/hip_bf16.h>
#include <stdint.h>

#define IN_F 128
#define EDGE_F 6
#define KC 136          // 128 node feats + 6 edge feats + deg + pad
#define NPB 32          // dst nodes per block in gemm

__device__ __forceinline__ float bf2f(unsigned short u) {
    return __uint_as_float(((unsigned int)u) << 16);
}
__device__ __forceinline__ unsigned short f2bfbits(float f) {
    __hip_bfloat16 h = __float2bfloat16(f);  // RNE
    return *reinterpret_cast<unsigned short*>(&h);
}
__device__ __forceinline__ unsigned int packbf(float a, float b) {
    return ((unsigned int)f2bfbits(b) << 16) | (unsigned int)f2bfbits(a);
}

// ---- Phase 1: per-dst degree histogram (1 atomic/edge) ----
__global__ __launch_bounds__(256) void hist(
        const int* __restrict__ eidx, int* __restrict__ cnt, int n_edges) {
    int e = blockIdx.x * 256 + threadIdx.x;
    if (e >= n_edges) return;
    atomicAdd(&cnt[eidx[2 * e + 1]], 1);
}

// ---- Phase 2: two-level exclusive scan of cnt -> rowptr (+cursor copy) ----
__global__ __launch_bounds__(256) void scan_a(
        const int* __restrict__ cnt, int* __restrict__ bsum, int n) {
    __shared__ int sh[256];
    int tid = threadIdx.x;
    int i = blockIdx.x * 256 + tid;
    sh[tid] = (i < n) ? cnt[i] : 0;
    __syncthreads();
    for (int off = 128; off > 0; off >>= 1) {
        if (tid < off) sh[tid] += sh[tid + off];
        __syncthreads();
    }
    if (tid == 0) bsum[blockIdx.x] = sh[0];
}

__global__ __launch_bounds__(256) void scan_b(
        const int* __restrict__ bsum, int* __restrict__ boff, int nblocks) {
    __shared__ int sh[256];
    int tid = threadIdx.x;
    int v = (tid < nblocks) ? bsum[tid] : 0;
    sh[tid] = v;
    __syncthreads();
    for (int off = 1; off < 256; off <<= 1) {
        int t = (tid >= off) ? sh[tid - off] : 0;
        __syncthreads();
        sh[tid] += t;
        __syncthreads();
    }
    boff[tid] = sh[tid] - v;  // exclusive
}

__global__ __launch_bounds__(256) void scan_c(
        const int* __restrict__ cnt, const int* __restrict__ boff,
        int* __restrict__ rowptr, int* __restrict__ cursor, int n) {
    __shared__ int sh[256];
    int tid = threadIdx.x;
    int i = blockIdx.x * 256 + tid;
    int v = (i < n) ? cnt[i] : 0;
    sh[tid] = v;
    __syncthreads();
    for (int off = 1; off < 256; off <<= 1) {
        int t = (tid >= off) ? sh[tid - off] : 0;
        __syncthreads();
        sh[tid] += t;
        __syncthreads();
    }
    int rp = boff[blockIdx.x] + sh[tid] - v;  // exclusive global prefix
    if (i < n) {
        rowptr[i] = rp;
        cursor[i] = rp;
        if (i == n - 1) rowptr[n] = rp + v;
    }
}

// ---- Phase 3: build 16B CSR records {src:int, ef:6xbf16} ----
// One aligned 16B scattered store per edge (was 28B over two streams).
__global__ __launch_bounds__(256) void fill_csr(
        const int* __restrict__ eidx, const float* __restrict__ ef,
        int* __restrict__ cursor, uint4* __restrict__ rec, int n_edges) {
    int e = blockIdx.x * 256 + threadIdx.x;
    if (e >= n_edges) return;
    const int2 pr = reinterpret_cast<const int2*>(eidx)[e];  // (src, dst)
    const float2* efs = reinterpret_cast<const float2*>(ef + (size_t)e * EDGE_F);
    const float2 f0 = efs[0], f1 = efs[1], f2 = efs[2];
    int pos = atomicAdd(&cursor[pr.y], 1);
    uint4 q;
    q.x = (unsigned int)pr.x;
    q.y = packbf(f0.x, f0.y);
    q.z = packbf(f1.x, f1.y);
    q.w = packbf(f2.x, f2.y);
    rec[pos] = q;
}

// ---- Phase 4: aggregate. One 64-lane wave per dst node; lane = 2 feats. ----
// Zero LDS, ~24 VGPR -> full 32-waves/CU occupancy for latency hiding.
// rec[i] is wave-uniform -> scalar s_load_dwordx4 (src + edge feats in one txn).
__global__ __launch_bounds__(256) void aggregate(
        const float* __restrict__ nf, const uint4* __restrict__ rec,
        const int* __restrict__ rowptr, unsigned short* __restrict__ S,
        int n_nodes) {
    const int lane = threadIdx.x & 63;
    const int wv = __builtin_amdgcn_readfirstlane(threadIdx.x >> 6);
    const int n = blockIdx.x * 4 + wv;
    if (n >= n_nodes) return;
    const int r0 = rowptr[n], r1 = rowptr[n + 1];
    const int deg = r1 - r0;
    float ax = 0.f, ay = 0.f;
    float e0 = 0.f, e1 = 0.f, e2 = 0.f, e3 = 0.f, e4 = 0.f, e5 = 0.f;
    int i = r0;
    for (; i + 3 < r1; i += 4) {  // 4 rows + 4 scalar recs in flight
        const uint4 q0 = rec[i], q1 = rec[i + 1], q2 = rec[i + 2], q3 = rec[i + 3];
        const float2 v0 = reinterpret_cast<const float2*>(nf + (size_t)(int)q0.x * IN_F)[lane];
        const float2 v1 = reinterpret_cast<const float2*>(nf + (size_t)(int)q1.x * IN_F)[lane];
        const float2 v2 = reinterpret_cast<const float2*>(nf + (size_t)(int)q2.x * IN_F)[lane];
        const float2 v3 = reinterpret_cast<const float2*>(nf + (size_t)(int)q3.x * IN_F)[lane];
        ax += (v0.x + v1.x) + (v2.x + v3.x);
        ay += (v0.y + v1.y) + (v2.y + v3.y);
        e0 += (bf2f((unsigned short)q0.y) + bf2f((unsigned short)q1.y))
            + (bf2f((unsigned short)q2.y) + bf2f((unsigned short)q3.y));
        e1 += (bf2f((unsigned short)(q0.y >> 16)) + bf2f((unsigned short)(q1.y >> 16)))
            + (bf2f((unsigned short)(q2.y >> 16)) + bf2f((unsigned short)(q3.y >> 16)));
        e2 += (bf2f((unsigned short)q0.z) + bf2f((unsigned short)q1.z))
            + (bf2f((unsigned short)q2.z) + bf2f((unsigned short)q3.z));
        e3 += (bf2f((unsigned short)(q0.z >> 16)) + bf2f((unsigned short)(q1.z >> 16)))
            + (bf2f((unsigned short)(q2.z >> 16)) + bf2f((unsigned short)(q3.z >> 16)));
        e4 += (bf2f((unsigned short)q0.w) + bf2f((unsigned short)q1.w))
            + (bf2f((unsigned short)q2.w) + bf2f((unsigned short)q3.w));
        e5 += (bf2f((unsigned short)(q0.w >> 16)) + bf2f((unsigned short)(q1.w >> 16)))
            + (bf2f((unsigned short)(q2.w >> 16)) + bf2f((unsigned short)(q3.w >> 16)));
    }
    for (; i < r1; ++i) {
        const uint4 q0 = rec[i];
        const float2 v0 = reinterpret_cast<const float2*>(nf + (size_t)(int)q0.x * IN_F)[lane];
        ax += v0.x; ay += v0.y;
        e0 += bf2f((unsigned short)q0.y); e1 += bf2f((unsigned short)(q0.y >> 16));
        e2 += bf2f((unsigned short)q0.z); e3 += bf2f((unsigned short)(q0.z >> 16));
        e4 += bf2f((unsigned short)q0.w); e5 += bf2f((unsigned short)(q0.w >> 16));
    }
    unsigned short* row = S + (size_t)n * KC;   // 272B rows, 16B aligned
    ushort2 o; o.x = f2bfbits(ax); o.y = f2bfbits(ay);
    reinterpret_cast<ushort2*>(row)[lane] = o;  // feats 2*lane, 2*lane+1
    if (lane == 0) {
        ushort4 ea, eb;
        ea.x = f2bfbits(e0); ea.y = f2bfbits(e1); ea.z = f2bfbits(e2); ea.w = f2bfbits(e3);
        eb.x = f2bfbits(e4); eb.y = f2bfbits(e5);
        eb.z = f2bfbits((float)deg);            // deg<=~50, exact in bf16
        eb.w = 0;
        reinterpret_cast<ushort4*>(row + 128)[0] = ea;
        reinterpret_cast<ushort4*>(row + 132)[0] = eb;
    }
}

// ---- Phase 5: dense GEMM  out = relu( S[N,136](bf16) @ Wcat[136,128](bf16) ) ----
__global__ __launch_bounds__(256) void gemm(
        const unsigned short* __restrict__ S,
        const float* __restrict__ W, const float* __restrict__ b,
        const float* __restrict__ We, const float* __restrict__ be,
        float* __restrict__ out, int n_nodes) {
    __shared__ __align__(16) unsigned short Wl[KC * 128];
    __shared__ __align__(16) float Xl[NPB * KC];
    const int tid = threadIdx.x;

    // Stage Wcat = [W ; We ; b+be ; 0] as bf16.
    for (int idx = tid; idx < KC * 128; idx += 256) {
        int k = idx >> 7, c = idx & 127;
        unsigned short v;
        if (k < 128)       v = f2bfbits(W[k * 128 + c]);
        else if (k < 134)  v = f2bfbits(We[(k - 128) * 128 + c]);
        else if (k == 134) v = f2bfbits(b[c] + be[c]);
        else               v = 0;
        Wl[idx] = v;
    }

    const int nb0 = blockIdx.x * NPB;
    const int rows = min(NPB, n_nodes - nb0);
    const int lim = rows * (KC / 8);  // ushort8 units of valid S data
    // Stage Xl (bf16 -> fp32), flat copy of NPB rows.
    for (int idx = tid; idx < NPB * KC / 8; idx += 256) {
        float4 lo = {0.f, 0.f, 0.f, 0.f}, hi = {0.f, 0.f, 0.f, 0.f};
        if (idx < lim) {
            const uint4 u = reinterpret_cast<const uint4*>(S + (size_t)nb0 * KC)[idx];
            lo.x = bf2f((unsigned short)u.x); lo.y = bf2f((unsigned short)(u.x >> 16));
            lo.z = bf2f((unsigned short)u.y); lo.w = bf2f((unsigned short)(u.y >> 16));
            hi.x = bf2f((unsigned short)u.z); hi.y = bf2f((unsigned short)(u.z >> 16));
            hi.z = bf2f((unsigned short)u.w); hi.w = bf2f((unsigned short)(u.w >> 16));
        }
        reinterpret_cast<float4*>(Xl)[2 * idx]     = lo;
        reinterpret_cast<float4*>(Xl)[2 * idx + 1] = hi;
    }
    __syncthreads();

    const int f0 = (tid & 31) * 4;
    const int ngrp = tid >> 5;

    float acc[4][4];
#pragma unroll
    for (int j = 0; j < 4; ++j)
#pragma unroll
        for (int i = 0; i < 4; ++i) acc[j][i] = 0.f;

    for (int k = 0; k < KC; ++k) {
        const ushort4 wu = *reinterpret_cast<const ushort4*>(&Wl[k * 128 + f0]);
        const float w0 = bf2f(wu.x), w1 = bf2f(wu.y), w2 = bf2f(wu.z), w3 = bf2f(wu.w);
#pragma unroll
        for (int j = 0; j < 4; ++j) {
            const float x = Xl[(ngrp + 8 * j) * KC + k];
            acc[j][0] += x * w0;
            acc[j][1] += x * w1;
            acc[j][2] += x * w2;
            acc[j][3] += x * w3;
        }
    }

#pragma unroll
    for (int j = 0; j < 4; ++j) {
        const int n = nb0 + ngrp + 8 * j;
        if (n < n_nodes) {
            float4 o;
            o.x = fmaxf(acc[j][0], 0.f);
            o.y = fmaxf(acc[j][1], 0.f);
            o.z = fmaxf(acc[j][2], 0.f);
            o.w = fmaxf(acc[j][3], 0.f);
            *reinterpret_cast<float4*>(&out[(size_t)n * 128 + f0]) = o;
        }
    }
}

extern "C" void kernel_launch(void* const* d_in, const int* in_sizes, int n_in,
                              void* d_out, int out_size, void* d_ws, size_t ws_size,
                              hipStream_t stream) {
    const float* nf = (const float*)d_in[0];  // fp32 (N,128)
    const int* eidx = (const int*)d_in[1];    // int32 (E,2)
    const float* ef = (const float*)d_in[2];  // fp32 (E,6)
    const float* W  = (const float*)d_in[3];  // fp32 (128,128)
    const float* b  = (const float*)d_in[4];  // fp32 (128,)
    const float* We = (const float*)d_in[5];  // fp32 (6,128)
    const float* be = (const float*)d_in[6];  // fp32 (128,)
    float* out = (float*)d_out;               // fp32 (N,128)

    const int n_nodes = in_sizes[0] / IN_F;
    const int n_edges = in_sizes[1] / 2;

    // ws: rec 16B*E (12.8MB) | S bf16 N*136 (13.6MB) | cnt N | rowptr N+1 | cursor N | bsum 256 | boff 256
    // total ~27.0MB <= proven-available 27.2MB.
    uint4* rec = (uint4*)d_ws;
    unsigned short* S = (unsigned short*)(rec + n_edges);
    int* cnt    = (int*)(S + (size_t)n_nodes * KC);
    int* rowptr = cnt + n_nodes;
    int* cursor = rowptr + n_nodes + 1;
    int* bsum   = cursor + n_nodes;
    int* boff   = bsum + 256;

    hipMemsetAsync(cnt, 0, (size_t)n_nodes * 4, stream);

    const int eb = (n_edges + 255) / 256;
    const int nb = (n_nodes + 255) / 256;  // 196 <= 256 (scan_b capacity)

    hist<<<eb, 256, 0, stream>>>(eidx, cnt, n_edges);
    scan_a<<<nb, 256, 0, stream>>>(cnt, bsum, n_nodes);
    scan_b<<<1, 256, 0, stream>>>(bsum, boff, nb);
    scan_c<<<nb, 256, 0, stream>>>(cnt, boff, rowptr, cursor, n_nodes);
    fill_csr<<<eb, 256, 0, stream>>>(eidx, ef, cursor, rec, n_edges);

    aggregate<<<(n_nodes + 3) / 4, 256, 0, stream>>>(nf, rec, rowptr, S, n_nodes);

    const int nt = (n_nodes + NPB - 1) / NPB;
    gemm<<<nt, 256, 0, stream>>>(S, W, b, We, be, out, n_nodes);
}

// Round 6
// 226.158 us; speedup vs baseline: 2.5915x; 1.3359x over previous
//
#include <hip/hip_runtime.h>
#include <hip/hip_bf16.h>
#include <stdint.h>

#define IN_F 128
#define EDGE_F 6

using bf16x8 = __attribute__((ext_vector_type(8))) short;  // 8 bf16 = 4 VGPRs
using f32x4  = __attribute__((ext_vector_type(4))) float;

__device__ __forceinline__ float bf2f(unsigned short u) {
    return __uint_as_float(((unsigned int)u) << 16);
}
__device__ __forceinline__ unsigned short f2bfbits(float f) {
    __hip_bfloat16 h = __float2bfloat16(f);  // RNE
    return *reinterpret_cast<unsigned short*>(&h);
}
__device__ __forceinline__ unsigned int packbf(float a, float b) {
    return ((unsigned int)f2bfbits(b) << 16) | (unsigned int)f2bfbits(a);
}

// ---- Phase 1: degree histogram; atomic return value = edge's rank in bucket ----
__global__ __launch_bounds__(256) void hist(
        const int* __restrict__ eidx, int* __restrict__ cnt,
        int* __restrict__ rank, int n_edges) {
    int e = blockIdx.x * 256 + threadIdx.x;
    if (e >= n_edges) return;
    rank[e] = atomicAdd(&cnt[eidx[2 * e + 1]], 1);
}

// ---- Phase 2: two-level exclusive scan of cnt -> rowptr ----
__global__ __launch_bounds__(256) void scan_a(
        const int* __restrict__ cnt, int* __restrict__ bsum, int n) {
    __shared__ int sh[256];
    int tid = threadIdx.x;
    int i = blockIdx.x * 256 + tid;
    sh[tid] = (i < n) ? cnt[i] : 0;
    __syncthreads();
    for (int off = 128; off > 0; off >>= 1) {
        if (tid < off) sh[tid] += sh[tid + off];
        __syncthreads();
    }
    if (tid == 0) bsum[blockIdx.x] = sh[0];
}

// scan_b + weight packing fused (both tiny, single block, independent outputs).
// Wpack layout: idx = ((kb*8+ft)*64+lane)*8+j  ->  bf16(W[kb*32+(lane>>4)*8+j][ft*16+(lane&15)])
// (B-operand fragment layout for mfma_f32_16x16x32_bf16, ready for ds_read_b128.)
// W2pack[j*128+f]: j<6 -> We[j][f]; j==6 -> b[f]+be[f]; j==7 -> 0.
__global__ __launch_bounds__(256) void scan_b_prep(
        const int* __restrict__ bsum, int* __restrict__ boff, int nblocks,
        const float* __restrict__ W, const float* __restrict__ b,
        const float* __restrict__ We, const float* __restrict__ be,
        unsigned short* __restrict__ Wpack, float* __restrict__ W2pack) {
    __shared__ int sh[256];
    int tid = threadIdx.x;
    int v = (tid < nblocks) ? bsum[tid] : 0;
    sh[tid] = v;
    __syncthreads();
    for (int off = 1; off < 256; off <<= 1) {
        int t = (tid >= off) ? sh[tid - off] : 0;
        __syncthreads();
        sh[tid] += t;
        __syncthreads();
    }
    boff[tid] = sh[tid] - v;  // exclusive

    for (int idx = tid; idx < 16384; idx += 256) {
        int j = idx & 7, lane = (idx >> 3) & 63, ft = (idx >> 9) & 7, kb = idx >> 12;
        int k = kb * 32 + (lane >> 4) * 8 + j;
        int f = ft * 16 + (lane & 15);
        Wpack[idx] = f2bfbits(W[k * 128 + f]);
    }
    for (int idx = tid; idx < 1024; idx += 256) {
        int j = idx >> 7, f = idx & 127;
        float w = 0.f;
        if (j < 6)       w = We[j * 128 + f];
        else if (j == 6) w = b[f] + be[f];
        W2pack[idx] = w;
    }
}

__global__ __launch_bounds__(256) void scan_c(
        const int* __restrict__ cnt, const int* __restrict__ boff,
        int* __restrict__ rowptr, int n) {
    __shared__ int sh[256];
    int tid = threadIdx.x;
    int i = blockIdx.x * 256 + tid;
    int v = (i < n) ? cnt[i] : 0;
    sh[tid] = v;
    __syncthreads();
    for (int off = 1; off < 256; off <<= 1) {
        int t = (tid >= off) ? sh[tid - off] : 0;
        __syncthreads();
        sh[tid] += t;
        __syncthreads();
    }
    int rp = boff[blockIdx.x] + sh[tid] - v;  // exclusive global prefix
    if (i < n) {
        rowptr[i] = rp;
        if (i == n - 1) rowptr[n] = rp + v;
    }
}

// ---- Phase 3: build 16B CSR records {src:int, ef:6xbf16}; NO atomic (rank-based) ----
__global__ __launch_bounds__(256) void fill_csr(
        const int* __restrict__ eidx, const float* __restrict__ ef,
        const int* __restrict__ rowptr, const int* __restrict__ rank,
        uint4* __restrict__ rec, int n_edges) {
    int e = blockIdx.x * 256 + threadIdx.x;
    if (e >= n_edges) return;
    const int2 pr = reinterpret_cast<const int2*>(eidx)[e];  // (src, dst)
    const float2* efs = reinterpret_cast<const float2*>(ef + (size_t)e * EDGE_F);
    const float2 f0 = efs[0], f1 = efs[1], f2 = efs[2];
    const int pos = rowptr[pr.y] + rank[e];
    uint4 q;
    q.x = (unsigned int)pr.x;
    q.y = packbf(f0.x, f0.y);
    q.z = packbf(f1.x, f1.y);
    q.w = packbf(f2.x, f2.y);
    rec[pos] = q;
}

// ---- Phase 4: aggregate. One 64-lane wave per dst node; lane = 2 feats. ----
// S row: 128 bf16 (stride 128). E8 row: {e0..e5, deg, 0} bf16 (16B).
__global__ __launch_bounds__(256) void aggregate(
        const float* __restrict__ nf, const uint4* __restrict__ rec,
        const int* __restrict__ rowptr, unsigned short* __restrict__ S,
        unsigned short* __restrict__ E8, int n_nodes) {
    const int lane = threadIdx.x & 63;
    const int wv = __builtin_amdgcn_readfirstlane(threadIdx.x >> 6);
    const int n = blockIdx.x * 4 + wv;
    if (n >= n_nodes) return;
    const int r0 = rowptr[n], r1 = rowptr[n + 1];
    const int deg = r1 - r0;
    float ax = 0.f, ay = 0.f;
    float e0 = 0.f, e1 = 0.f, e2 = 0.f, e3 = 0.f, e4 = 0.f, e5 = 0.f;
    int i = r0;
    for (; i + 3 < r1; i += 4) {  // 4 rows + 4 scalar recs in flight
        const uint4 q0 = rec[i], q1 = rec[i + 1], q2 = rec[i + 2], q3 = rec[i + 3];
        const float2 v0 = reinterpret_cast<const float2*>(nf + (size_t)(int)q0.x * IN_F)[lane];
        const float2 v1 = reinterpret_cast<const float2*>(nf + (size_t)(int)q1.x * IN_F)[lane];
        const float2 v2 = reinterpret_cast<const float2*>(nf + (size_t)(int)q2.x * IN_F)[lane];
        const float2 v3 = reinterpret_cast<const float2*>(nf + (size_t)(int)q3.x * IN_F)[lane];
        ax += (v0.x + v1.x) + (v2.x + v3.x);
        ay += (v0.y + v1.y) + (v2.y + v3.y);
        e0 += (bf2f((unsigned short)q0.y) + bf2f((unsigned short)q1.y))
            + (bf2f((unsigned short)q2.y) + bf2f((unsigned short)q3.y));
        e1 += (bf2f((unsigned short)(q0.y >> 16)) + bf2f((unsigned short)(q1.y >> 16)))
            + (bf2f((unsigned short)(q2.y >> 16)) + bf2f((unsigned short)(q3.y >> 16)));
        e2 += (bf2f((unsigned short)q0.z) + bf2f((unsigned short)q1.z))
            + (bf2f((unsigned short)q2.z) + bf2f((unsigned short)q3.z));
        e3 += (bf2f((unsigned short)(q0.z >> 16)) + bf2f((unsigned short)(q1.z >> 16)))
            + (bf2f((unsigned short)(q2.z >> 16)) + bf2f((unsigned short)(q3.z >> 16)));
        e4 += (bf2f((unsigned short)q0.w) + bf2f((unsigned short)q1.w))
            + (bf2f((unsigned short)q2.w) + bf2f((unsigned short)q3.w));
        e5 += (bf2f((unsigned short)(q0.w >> 16)) + bf2f((unsigned short)(q1.w >> 16)))
            + (bf2f((unsigned short)(q2.w >> 16)) + bf2f((unsigned short)(q3.w >> 16)));
    }
    for (; i < r1; ++i) {
        const uint4 q0 = rec[i];
        const float2 v0 = reinterpret_cast<const float2*>(nf + (size_t)(int)q0.x * IN_F)[lane];
        ax += v0.x; ay += v0.y;
        e0 += bf2f((unsigned short)q0.y); e1 += bf2f((unsigned short)(q0.y >> 16));
        e2 += bf2f((unsigned short)q0.z); e3 += bf2f((unsigned short)(q0.z >> 16));
        e4 += bf2f((unsigned short)q0.w); e5 += bf2f((unsigned short)(q0.w >> 16));
    }
    unsigned short* row = S + (size_t)n * IN_F;
    ushort2 o; o.x = f2bfbits(ax); o.y = f2bfbits(ay);
    reinterpret_cast<ushort2*>(row)[lane] = o;  // feats 2*lane, 2*lane+1
    if (lane == 0) {
        uint4 q;
        q.x = packbf(e0, e1);
        q.y = packbf(e2, e3);
        q.z = packbf(e4, e5);
        q.w = packbf((float)deg, 0.f);          // deg exact in bf16 (small)
        *reinterpret_cast<uint4*>(E8 + (size_t)n * 8) = q;
    }
}

// ---- Phase 5: MFMA GEMM  out = relu( S[N,128]bf16 @ W[128,128]bf16 + E-term ) ----
// Block = 4 waves = 64 rows x 128 cols. Wave: 16x128 via 8 f-tiles x 4 K-steps
// of mfma_f32_16x16x32_bf16. A from global S (16B/lane), B from LDS Wpack.
// Epilogue adds rank-7 edge term in fp32: sum_j e[j]*We[j][f] + deg*(b+be)[f].
__global__ __launch_bounds__(256) void gemm_mfma(
        const unsigned short* __restrict__ S, const unsigned short* __restrict__ E8,
        const unsigned short* __restrict__ Wpack, const float* __restrict__ W2pack,
        float* __restrict__ out, int n_nodes) {
    __shared__ __align__(16) short Wl[16384];   // 32 KB, B-fragment layout
    __shared__ float W2l[1024];                 // 4 KB
    const int tid = threadIdx.x;
    for (int i = tid; i < 2048; i += 256)
        reinterpret_cast<uint4*>(Wl)[i] = reinterpret_cast<const uint4*>(Wpack)[i];
    for (int i = tid; i < 1024; i += 256) W2l[i] = W2pack[i];

    const int wv = tid >> 6, lane = tid & 63;
    const int m = lane & 15, quad = lane >> 4;
    const int n0 = blockIdx.x * 64 + wv * 16;

    // A fragments: A[m=lane&15][k=quad*8+j], k-step kb adds kb*32.
    const int arow = min(n0 + m, n_nodes - 1);
    const unsigned short* ap = S + (size_t)arow * IN_F + quad * 8;
    bf16x8 a[4];
#pragma unroll
    for (int kb = 0; kb < 4; ++kb)
        a[kb] = *reinterpret_cast<const bf16x8*>(ap + kb * 32);

    __syncthreads();

    f32x4 acc[8];
#pragma unroll
    for (int ft = 0; ft < 8; ++ft) acc[ft] = (f32x4){0.f, 0.f, 0.f, 0.f};

#pragma unroll
    for (int kb = 0; kb < 4; ++kb) {
#pragma unroll
        for (int ft = 0; ft < 8; ++ft) {
            const bf16x8 bfrag =
                reinterpret_cast<const bf16x8*>(Wl)[(kb * 8 + ft) * 64 + lane];
            acc[ft] = __builtin_amdgcn_mfma_f32_16x16x32_bf16(a[kb], bfrag, acc[ft], 0, 0, 0);
        }
    }

    // Epilogue. C/D layout: col=lane&15, row=quad*4+reg (m89-verified).
    float e[4][7];
#pragma unroll
    for (int r = 0; r < 4; ++r) {
        const int n = min(n0 + quad * 4 + r, n_nodes - 1);
        const uint4 q = *reinterpret_cast<const uint4*>(E8 + (size_t)n * 8);
        e[r][0] = bf2f((unsigned short)q.x); e[r][1] = bf2f((unsigned short)(q.x >> 16));
        e[r][2] = bf2f((unsigned short)q.y); e[r][3] = bf2f((unsigned short)(q.y >> 16));
        e[r][4] = bf2f((unsigned short)q.z); e[r][5] = bf2f((unsigned short)(q.z >> 16));
        e[r][6] = bf2f((unsigned short)q.w);  // deg
    }
#pragma unroll
    for (int ft = 0; ft < 8; ++ft) {
        const int f = ft * 16 + m;
        float w2[7];
#pragma unroll
        for (int j = 0; j < 7; ++j) w2[j] = W2l[j * 128 + f];
#pragma unroll
        for (int r = 0; r < 4; ++r) {
            const int n = n0 + quad * 4 + r;
            if (n < n_nodes) {
                float v = acc[ft][r];
#pragma unroll
                for (int j = 0; j < 7; ++j) v += e[r][j] * w2[j];
                out[(size_t)n * 128 + f] = fmaxf(v, 0.f);
            }
        }
    }
}

extern "C" void kernel_launch(void* const* d_in, const int* in_sizes, int n_in,
                              void* d_out, int out_size, void* d_ws, size_t ws_size,
                              hipStream_t stream) {
    const float* nf = (const float*)d_in[0];  // fp32 (N,128)
    const int* eidx = (const int*)d_in[1];    // int32 (E,2)
    const float* ef = (const float*)d_in[2];  // fp32 (E,6)
    const float* W  = (const float*)d_in[3];  // fp32 (128,128)
    const float* b  = (const float*)d_in[4];  // fp32 (128,)
    const float* We = (const float*)d_in[5];  // fp32 (6,128)
    const float* be = (const float*)d_in[6];  // fp32 (128,)
    float* out = (float*)d_out;               // fp32 (N,128)

    const int n_nodes = in_sizes[0] / IN_F;
    const int n_edges = in_sizes[1] / 2;

    // ws: rec 16B*E | S bf16 N*128 (rank int*E aliased: dead before aggregate)
    //   | E8 bf16 N*8 | Wpack 32KB | W2pack 4KB | cnt N | rowptr N+1 | bsum | boff
    // total ~26.84 MB (< proven 27.2 MB).
    uint4* rec = (uint4*)d_ws;
    unsigned short* S = (unsigned short*)(rec + n_edges);
    int* rank = (int*)S;  // alias: written by hist, read by fill_csr, dead after
    unsigned short* E8 = S + (size_t)n_nodes * IN_F;
    unsigned short* Wpack = E8 + (size_t)n_nodes * 8;
    float* W2pack = (float*)(Wpack + 16384);
    int* cnt    = (int*)(W2pack + 1024);
    int* rowptr = cnt + n_nodes;
    int* bsum   = rowptr + n_nodes + 1;
    int* boff   = bsum + 256;

    hipMemsetAsync(cnt, 0, (size_t)n_nodes * 4, stream);

    const int eb = (n_edges + 255) / 256;
    const int nb = (n_nodes + 255) / 256;  // 196 <= 256 (scan capacity)

    hist<<<eb, 256, 0, stream>>>(eidx, cnt, rank, n_edges);
    scan_a<<<nb, 256, 0, stream>>>(cnt, bsum, n_nodes);
    scan_b_prep<<<1, 256, 0, stream>>>(bsum, boff, nb, W, b, We, be, Wpack, W2pack);
    scan_c<<<nb, 256, 0, stream>>>(cnt, boff, rowptr, n_nodes);
    fill_csr<<<eb, 256, 0, stream>>>(eidx, ef, rowptr, rank, rec, n_edges);

    aggregate<<<(n_nodes + 3) / 4, 256, 0, stream>>>(nf, rec, rowptr, S, E8, n_nodes);

    gemm_mfma<<<(n_nodes + 63) / 64, 256, 0, stream>>>(S, E8, Wpack, W2pack, out, n_nodes);
}

// Round 7
// 213.771 us; speedup vs baseline: 2.7416x; 1.0579x over previous
//
#include <hip/hip_runtime.h>
#include <hip/hip_bf16.h>
#include <stdint.h>

#define IN_F 128
#define EDGE_F 6

using bf16x8 = __attribute__((ext_vector_type(8))) short;  // 8 bf16 = 4 VGPRs
using f32x4  = __attribute__((ext_vector_type(4))) float;

__device__ __forceinline__ float bf2f(unsigned short u) {
    return __uint_as_float(((unsigned int)u) << 16);
}
__device__ __forceinline__ unsigned short f2bfbits(float f) {
    __hip_bfloat16 h = __float2bfloat16(f);  // RNE
    return *reinterpret_cast<unsigned short*>(&h);
}
__device__ __forceinline__ unsigned int packbf(float a, float b) {
    return ((unsigned int)f2bfbits(b) << 16) | (unsigned int)f2bfbits(a);
}

// ---- Phase 1: degree histogram (atomic return = edge's rank) + nf->bf16 cast ----
// hist is atomic-latency-bound (VALU+BW idle) so the BW-bound cast rides along.
__global__ __launch_bounds__(256) void hist_cast(
        const int* __restrict__ eidx, int* __restrict__ cnt,
        int* __restrict__ rank, int n_edges,
        const float* __restrict__ nf, unsigned short* __restrict__ nfb,
        int n_cast) {  // n_cast = N*128/8 ushort8 units (0 => no cast)
    const int t = blockIdx.x * 256 + threadIdx.x;
    if (t < n_edges) rank[t] = atomicAdd(&cnt[eidx[2 * t + 1]], 1);
    const int stride = gridDim.x * 256;
    for (int i = t; i < n_cast; i += stride) {
        const float4 lo = reinterpret_cast<const float4*>(nf)[2 * i];
        const float4 hi = reinterpret_cast<const float4*>(nf)[2 * i + 1];
        uint4 o;
        o.x = packbf(lo.x, lo.y); o.y = packbf(lo.z, lo.w);
        o.z = packbf(hi.x, hi.y); o.w = packbf(hi.z, hi.w);
        reinterpret_cast<uint4*>(nfb)[i] = o;
    }
}

// ---- Phase 2: two-level exclusive scan of cnt -> rowptr ----
__global__ __launch_bounds__(256) void scan_a(
        const int* __restrict__ cnt, int* __restrict__ bsum, int n) {
    __shared__ int sh[256];
    int tid = threadIdx.x;
    int i = blockIdx.x * 256 + tid;
    sh[tid] = (i < n) ? cnt[i] : 0;
    __syncthreads();
    for (int off = 128; off > 0; off >>= 1) {
        if (tid < off) sh[tid] += sh[tid + off];
        __syncthreads();
    }
    if (tid == 0) bsum[blockIdx.x] = sh[0];
}

// scan_b + weight packing fused (both tiny, single block, independent outputs).
// Wpack: idx = ((kb*8+ft)*64+lane)*8+j -> bf16(W[kb*32+(lane>>4)*8+j][ft*16+(lane&15)])
// (B-operand fragment layout for mfma_f32_16x16x32_bf16.)
// W2pack[j*128+f]: j<6 -> We[j][f]; j==6 -> b[f]+be[f]; j==7 -> 0.
__global__ __launch_bounds__(256) void scan_b_prep(
        const int* __restrict__ bsum, int* __restrict__ boff, int nblocks,
        const float* __restrict__ W, const float* __restrict__ b,
        const float* __restrict__ We, const float* __restrict__ be,
        unsigned short* __restrict__ Wpack, float* __restrict__ W2pack) {
    __shared__ int sh[256];
    int tid = threadIdx.x;
    int v = (tid < nblocks) ? bsum[tid] : 0;
    sh[tid] = v;
    __syncthreads();
    for (int off = 1; off < 256; off <<= 1) {
        int t = (tid >= off) ? sh[tid - off] : 0;
        __syncthreads();
        sh[tid] += t;
        __syncthreads();
    }
    boff[tid] = sh[tid] - v;  // exclusive

    for (int idx = tid; idx < 16384; idx += 256) {
        int j = idx & 7, lane = (idx >> 3) & 63, ft = (idx >> 9) & 7, kb = idx >> 12;
        int k = kb * 32 + (lane >> 4) * 8 + j;
        int f = ft * 16 + (lane & 15);
        Wpack[idx] = f2bfbits(W[k * 128 + f]);
    }
    for (int idx = tid; idx < 1024; idx += 256) {
        int j = idx >> 7, f = idx & 127;
        float w = 0.f;
        if (j < 6)       w = We[j * 128 + f];
        else if (j == 6) w = b[f] + be[f];
        W2pack[idx] = w;
    }
}

__global__ __launch_bounds__(256) void scan_c(
        const int* __restrict__ cnt, const int* __restrict__ boff,
        int* __restrict__ rowptr, int n) {
    __shared__ int sh[256];
    int tid = threadIdx.x;
    int i = blockIdx.x * 256 + tid;
    int v = (i < n) ? cnt[i] : 0;
    sh[tid] = v;
    __syncthreads();
    for (int off = 1; off < 256; off <<= 1) {
        int t = (tid >= off) ? sh[tid - off] : 0;
        __syncthreads();
        sh[tid] += t;
        __syncthreads();
    }
    int rp = boff[blockIdx.x] + sh[tid] - v;  // exclusive global prefix
    if (i < n) {
        rowptr[i] = rp;
        if (i == n - 1) rowptr[n] = rp + v;
    }
}

// ---- Phase 3: build 16B CSR records {src:int, ef:6xbf16}; NO atomic ----
__global__ __launch_bounds__(256) void fill_csr(
        const int* __restrict__ eidx, const float* __restrict__ ef,
        const int* __restrict__ rowptr, const int* __restrict__ rank,
        uint4* __restrict__ rec, int n_edges) {
    int e = blockIdx.x * 256 + threadIdx.x;
    if (e >= n_edges) return;
    const int2 pr = reinterpret_cast<const int2*>(eidx)[e];  // (src, dst)
    const float2* efs = reinterpret_cast<const float2*>(ef + (size_t)e * EDGE_F);
    const float2 f0 = efs[0], f1 = efs[1], f2 = efs[2];
    const int pos = rowptr[pr.y] + rank[e];
    uint4 q;
    q.x = (unsigned int)pr.x;
    q.y = packbf(f0.x, f0.y);
    q.z = packbf(f1.x, f1.y);
    q.w = packbf(f2.x, f2.y);
    rec[pos] = q;
}

// ---- Phase 4a: aggregate, bf16 gather (256B rows). One wave per dst node. ----
__global__ __launch_bounds__(256) void aggregate_bf16(
        const unsigned short* __restrict__ nfb, const uint4* __restrict__ rec,
        const int* __restrict__ rowptr, unsigned short* __restrict__ S,
        unsigned short* __restrict__ E8, int n_nodes) {
    const int lane = threadIdx.x & 63;
    const int wv = __builtin_amdgcn_readfirstlane(threadIdx.x >> 6);
    const int n = blockIdx.x * 4 + wv;
    if (n >= n_nodes) return;
    const int r0 = rowptr[n], r1 = rowptr[n + 1];
    const int deg = r1 - r0;
    float ax = 0.f, ay = 0.f;
    float e0 = 0.f, e1 = 0.f, e2 = 0.f, e3 = 0.f, e4 = 0.f, e5 = 0.f;
    int i = r0;
    for (; i + 3 < r1; i += 4) {  // 4 gathers + 4 rec loads in flight
        const uint4 q0 = rec[i], q1 = rec[i + 1], q2 = rec[i + 2], q3 = rec[i + 3];
        const unsigned int u0 = reinterpret_cast<const unsigned int*>(nfb + (size_t)(int)q0.x * IN_F)[lane];
        const unsigned int u1 = reinterpret_cast<const unsigned int*>(nfb + (size_t)(int)q1.x * IN_F)[lane];
        const unsigned int u2 = reinterpret_cast<const unsigned int*>(nfb + (size_t)(int)q2.x * IN_F)[lane];
        const unsigned int u3 = reinterpret_cast<const unsigned int*>(nfb + (size_t)(int)q3.x * IN_F)[lane];
        ax += (bf2f((unsigned short)u0) + bf2f((unsigned short)u1))
            + (bf2f((unsigned short)u2) + bf2f((unsigned short)u3));
        ay += (bf2f((unsigned short)(u0 >> 16)) + bf2f((unsigned short)(u1 >> 16)))
            + (bf2f((unsigned short)(u2 >> 16)) + bf2f((unsigned short)(u3 >> 16)));
        e0 += (bf2f((unsigned short)q0.y) + bf2f((unsigned short)q1.y))
            + (bf2f((unsigned short)q2.y) + bf2f((unsigned short)q3.y));
        e1 += (bf2f((unsigned short)(q0.y >> 16)) + bf2f((unsigned short)(q1.y >> 16)))
            + (bf2f((unsigned short)(q2.y >> 16)) + bf2f((unsigned short)(q3.y >> 16)));
        e2 += (bf2f((unsigned short)q0.z) + bf2f((unsigned short)q1.z))
            + (bf2f((unsigned short)q2.z) + bf2f((unsigned short)q3.z));
        e3 += (bf2f((unsigned short)(q0.z >> 16)) + bf2f((unsigned short)(q1.z >> 16)))
            + (bf2f((unsigned short)(q2.z >> 16)) + bf2f((unsigned short)(q3.z >> 16)));
        e4 += (bf2f((unsigned short)q0.w) + bf2f((unsigned short)q1.w))
            + (bf2f((unsigned short)q2.w) + bf2f((unsigned short)q3.w));
        e5 += (bf2f((unsigned short)(q0.w >> 16)) + bf2f((unsigned short)(q1.w >> 16)))
            + (bf2f((unsigned short)(q2.w >> 16)) + bf2f((unsigned short)(q3.w >> 16)));
    }
    for (; i < r1; ++i) {
        const uint4 q0 = rec[i];
        const unsigned int u0 = reinterpret_cast<const unsigned int*>(nfb + (size_t)(int)q0.x * IN_F)[lane];
        ax += bf2f((unsigned short)u0); ay += bf2f((unsigned short)(u0 >> 16));
        e0 += bf2f((unsigned short)q0.y); e1 += bf2f((unsigned short)(q0.y >> 16));
        e2 += bf2f((unsigned short)q0.z); e3 += bf2f((unsigned short)(q0.z >> 16));
        e4 += bf2f((unsigned short)q0.w); e5 += bf2f((unsigned short)(q0.w >> 16));
    }
    unsigned short* row = S + (size_t)n * IN_F;
    reinterpret_cast<unsigned int*>(row)[lane] = packbf(ax, ay);
    if (lane == 0) {
        uint4 q;
        q.x = packbf(e0, e1);
        q.y = packbf(e2, e3);
        q.z = packbf(e4, e5);
        q.w = packbf((float)deg, 0.f);
        *reinterpret_cast<uint4*>(E8 + (size_t)n * 8) = q;
    }
}

// ---- Phase 4b: fallback aggregate, fp32 gather (if ws too small for nfb) ----
__global__ __launch_bounds__(256) void aggregate_f32(
        const float* __restrict__ nf, const uint4* __restrict__ rec,
        const int* __restrict__ rowptr, unsigned short* __restrict__ S,
        unsigned short* __restrict__ E8, int n_nodes) {
    const int lane = threadIdx.x & 63;
    const int wv = __builtin_amdgcn_readfirstlane(threadIdx.x >> 6);
    const int n = blockIdx.x * 4 + wv;
    if (n >= n_nodes) return;
    const int r0 = rowptr[n], r1 = rowptr[n + 1];
    const int deg = r1 - r0;
    float ax = 0.f, ay = 0.f;
    float e0 = 0.f, e1 = 0.f, e2 = 0.f, e3 = 0.f, e4 = 0.f, e5 = 0.f;
    int i = r0;
    for (; i + 3 < r1; i += 4) {
        const uint4 q0 = rec[i], q1 = rec[i + 1], q2 = rec[i + 2], q3 = rec[i + 3];
        const float2 v0 = reinterpret_cast<const float2*>(nf + (size_t)(int)q0.x * IN_F)[lane];
        const float2 v1 = reinterpret_cast<const float2*>(nf + (size_t)(int)q1.x * IN_F)[lane];
        const float2 v2 = reinterpret_cast<const float2*>(nf + (size_t)(int)q2.x * IN_F)[lane];
        const float2 v3 = reinterpret_cast<const float2*>(nf + (size_t)(int)q3.x * IN_F)[lane];
        ax += (v0.x + v1.x) + (v2.x + v3.x);
        ay += (v0.y + v1.y) + (v2.y + v3.y);
        e0 += (bf2f((unsigned short)q0.y) + bf2f((unsigned short)q1.y))
            + (bf2f((unsigned short)q2.y) + bf2f((unsigned short)q3.y));
        e1 += (bf2f((unsigned short)(q0.y >> 16)) + bf2f((unsigned short)(q1.y >> 16)))
            + (bf2f((unsigned short)(q2.y >> 16)) + bf2f((unsigned short)(q3.y >> 16)));
        e2 += (bf2f((unsigned short)q0.z) + bf2f((unsigned short)q1.z))
            + (bf2f((unsigned short)q2.z) + bf2f((unsigned short)q3.z));
        e3 += (bf2f((unsigned short)(q0.z >> 16)) + bf2f((unsigned short)(q1.z >> 16)))
            + (bf2f((unsigned short)(q2.z >> 16)) + bf2f((unsigned short)(q3.z >> 16)));
        e4 += (bf2f((unsigned short)q0.w) + bf2f((unsigned short)q1.w))
            + (bf2f((unsigned short)q2.w) + bf2f((unsigned short)q3.w));
        e5 += (bf2f((unsigned short)(q0.w >> 16)) + bf2f((unsigned short)(q1.w >> 16)))
            + (bf2f((unsigned short)(q2.w >> 16)) + bf2f((unsigned short)(q3.w >> 16)));
    }
    for (; i < r1; ++i) {
        const uint4 q0 = rec[i];
        const float2 v0 = reinterpret_cast<const float2*>(nf + (size_t)(int)q0.x * IN_F)[lane];
        ax += v0.x; ay += v0.y;
        e0 += bf2f((unsigned short)q0.y); e1 += bf2f((unsigned short)(q0.y >> 16));
        e2 += bf2f((unsigned short)q0.z); e3 += bf2f((unsigned short)(q0.z >> 16));
        e4 += bf2f((unsigned short)q0.w); e5 += bf2f((unsigned short)(q0.w >> 16));
    }
    unsigned short* row = S + (size_t)n * IN_F;
    reinterpret_cast<unsigned int*>(row)[lane] = packbf(ax, ay);
    if (lane == 0) {
        uint4 q;
        q.x = packbf(e0, e1);
        q.y = packbf(e2, e3);
        q.z = packbf(e4, e5);
        q.w = packbf((float)deg, 0.f);
        *reinterpret_cast<uint4*>(E8 + (size_t)n * 8) = q;
    }
}

// ---- Phase 5: MFMA GEMM  out = relu( S[N,128]bf16 @ W[128,128]bf16 + E-term ) ----
__global__ __launch_bounds__(256) void gemm_mfma(
        const unsigned short* __restrict__ S, const unsigned short* __restrict__ E8,
        const unsigned short* __restrict__ Wpack, const float* __restrict__ W2pack,
        float* __restrict__ out, int n_nodes) {
    __shared__ __align__(16) short Wl[16384];   // 32 KB, B-fragment layout
    __shared__ float W2l[1024];                 // 4 KB
    const int tid = threadIdx.x;
    for (int i = tid; i < 2048; i += 256)
        reinterpret_cast<uint4*>(Wl)[i] = reinterpret_cast<const uint4*>(Wpack)[i];
    for (int i = tid; i < 1024; i += 256) W2l[i] = W2pack[i];

    const int wv = tid >> 6, lane = tid & 63;
    const int m = lane & 15, quad = lane >> 4;
    const int n0 = blockIdx.x * 64 + wv * 16;

    const int arow = min(n0 + m, n_nodes - 1);
    const unsigned short* ap = S + (size_t)arow * IN_F + quad * 8;
    bf16x8 a[4];
#pragma unroll
    for (int kb = 0; kb < 4; ++kb)
        a[kb] = *reinterpret_cast<const bf16x8*>(ap + kb * 32);

    __syncthreads();

    f32x4 acc[8];
#pragma unroll
    for (int ft = 0; ft < 8; ++ft) acc[ft] = (f32x4){0.f, 0.f, 0.f, 0.f};

#pragma unroll
    for (int kb = 0; kb < 4; ++kb) {
#pragma unroll
        for (int ft = 0; ft < 8; ++ft) {
            const bf16x8 bfrag =
                reinterpret_cast<const bf16x8*>(Wl)[(kb * 8 + ft) * 64 + lane];
            acc[ft] = __builtin_amdgcn_mfma_f32_16x16x32_bf16(a[kb], bfrag, acc[ft], 0, 0, 0);
        }
    }

    float e[4][7];
#pragma unroll
    for (int r = 0; r < 4; ++r) {
        const int n = min(n0 + quad * 4 + r, n_nodes - 1);
        const uint4 q = *reinterpret_cast<const uint4*>(E8 + (size_t)n * 8);
        e[r][0] = bf2f((unsigned short)q.x); e[r][1] = bf2f((unsigned short)(q.x >> 16));
        e[r][2] = bf2f((unsigned short)q.y); e[r][3] = bf2f((unsigned short)(q.y >> 16));
        e[r][4] = bf2f((unsigned short)q.z); e[r][5] = bf2f((unsigned short)(q.z >> 16));
        e[r][6] = bf2f((unsigned short)q.w);  // deg
    }
#pragma unroll
    for (int ft = 0; ft < 8; ++ft) {
        const int f = ft * 16 + m;
        float w2[7];
#pragma unroll
        for (int j = 0; j < 7; ++j) w2[j] = W2l[j * 128 + f];
#pragma unroll
        for (int r = 0; r < 4; ++r) {
            const int n = n0 + quad * 4 + r;
            if (n < n_nodes) {
                float v = acc[ft][r];
#pragma unroll
                for (int j = 0; j < 7; ++j) v += e[r][j] * w2[j];
                out[(size_t)n * 128 + f] = fmaxf(v, 0.f);
            }
        }
    }
}

extern "C" void kernel_launch(void* const* d_in, const int* in_sizes, int n_in,
                              void* d_out, int out_size, void* d_ws, size_t ws_size,
                              hipStream_t stream) {
    const float* nf = (const float*)d_in[0];  // fp32 (N,128)
    const int* eidx = (const int*)d_in[1];    // int32 (E,2)
    const float* ef = (const float*)d_in[2];  // fp32 (E,6)
    const float* W  = (const float*)d_in[3];  // fp32 (128,128)
    const float* b  = (const float*)d_in[4];  // fp32 (128,)
    const float* We = (const float*)d_in[5];  // fp32 (6,128)
    const float* be = (const float*)d_in[6];  // fp32 (128,)
    float* out = (float*)d_out;               // fp32 (N,128)

    const int n_nodes = in_sizes[0] / IN_F;
    const int n_edges = in_sizes[1] / 2;

    // ws: rec 16B*E | S bf16 N*128 (rank aliased; dead before aggregate writes S)
    //   | E8 bf16 N*8 | Wpack 32KB | W2pack 4KB | cnt N | rowptr N+1 | bsum | boff
    //   | nfb bf16 N*128 (optional, only if ws_size permits)
    uint4* rec = (uint4*)d_ws;
    unsigned short* S = (unsigned short*)(rec + n_edges);
    int* rank = (int*)S;  // alias
    unsigned short* E8 = S + (size_t)n_nodes * IN_F;
    unsigned short* Wpack = E8 + (size_t)n_nodes * 8;
    float* W2pack = (float*)(Wpack + 16384);
    int* cnt    = (int*)(W2pack + 1024);
    int* rowptr = cnt + n_nodes;
    int* bsum   = rowptr + n_nodes + 1;
    int* boff   = bsum + 256;
    unsigned short* nfb = (unsigned short*)(boff + 256);

    const size_t need_bf16 = (size_t)((char*)(nfb + (size_t)n_nodes * IN_F) - (char*)d_ws);
    const bool use_bf16 = ws_size >= need_bf16;
    const int n_cast = use_bf16 ? n_nodes * (IN_F / 8) : 0;

    hipMemsetAsync(cnt, 0, (size_t)n_nodes * 4, stream);

    const int eb = (n_edges + 255) / 256;
    const int nb = (n_nodes + 255) / 256;  // 196 <= 256 (scan capacity)

    hist_cast<<<eb, 256, 0, stream>>>(eidx, cnt, rank, n_edges, nf, nfb, n_cast);
    scan_a<<<nb, 256, 0, stream>>>(cnt, bsum, n_nodes);
    scan_b_prep<<<1, 256, 0, stream>>>(bsum, boff, nb, W, b, We, be, Wpack, W2pack);
    scan_c<<<nb, 256, 0, stream>>>(cnt, boff, rowptr, n_nodes);
    fill_csr<<<eb, 256, 0, stream>>>(eidx, ef, rowptr, rank, rec, n_edges);

    const int ab = (n_nodes + 3) / 4;
    if (use_bf16)
        aggregate_bf16<<<ab, 256, 0, stream>>>(nfb, rec, rowptr, S, E8, n_nodes);
    else
        aggregate_f32<<<ab, 256, 0, stream>>>(nf, rec, rowptr, S, E8, n_nodes);

    gemm_mfma<<<(n_nodes + 63) / 64, 256, 0, stream>>>(S, E8, Wpack, W2pack, out, n_nodes);
}